// Round 1
// baseline (580.203 us; speedup 1.0000x reference)
//
#include <hip/hip_runtime.h>

constexpr int BROWS = 16384;
constexpr int DTOT  = 464;   // 8*50 + 64
constexpr int EDIM  = 50;
constexpr int CIN   = 64;
constexpr int H1S   = 256;
constexpr int H2S   = 128;
constexpr int NEXP  = 4;
constexpr int NTASK = 3;

// ---------------------------------------------------------------------------
// Kernel 1: embedding gather + continuous layer + FM term, builds x [B,464]
// and fm [B]. One block (256 thr) handles 16 rows.
// ---------------------------------------------------------------------------
__global__ __launch_bounds__(256)
void build_x_fm(const int* __restrict__ disc, const float* __restrict__ cf,
                const float* __restrict__ e0p, const float* __restrict__ e1p,
                const float* __restrict__ e2p, const float* __restrict__ e3p,
                const float* __restrict__ e4p, const float* __restrict__ e5p,
                const float* __restrict__ e6p, const float* __restrict__ e7p,
                const float* __restrict__ contW, const float* __restrict__ contB,
                const float* __restrict__ fmW,
                float* __restrict__ x, float* __restrict__ fm)
{
    __shared__ float xs[16][DTOT];
    __shared__ float cfs[16][CIN];
    __shared__ float xes[16][10];
    __shared__ const float* stabs[8];
    __shared__ int sdisc[16 * 8];

    const int t = threadIdx.x;
    const long row0 = (long)blockIdx.x * 16;

    if (t == 0) {
        stabs[0] = e0p; stabs[1] = e1p; stabs[2] = e2p; stabs[3] = e3p;
        stabs[4] = e4p; stabs[5] = e5p; stabs[6] = e6p; stabs[7] = e7p;
    }
    if (t < 128) sdisc[t] = disc[row0 * 8 + t];
    ((float4*)cfs)[t] = ((const float4*)(cf + row0 * CIN))[t];   // 16x64 = 256 float4
    __syncthreads();

    // gather embeddings into xs[:, 0:400]
    for (int idx = t; idx < 16 * 400; idx += 256) {
        const int r   = idx / 400;
        const int j   = idx - r * 400;
        const int tab = j / 50;
        const int off = j - tab * 50;
        const long fi = sdisc[r * 8 + tab];
        xs[r][j] = stabs[tab][fi * EDIM + off];
    }
    // continuous layer into xs[:, 400:464]
    for (int idx = t; idx < 16 * 64; idx += 256) {
        const int r = idx >> 6;
        const int o = idx & 63;
        float acc = contB[o];
#pragma unroll 8
        for (int k = 0; k < 64; ++k) acc = fmaf(cfs[r][k], contW[k * 64 + o], acc);
        xs[r][400 + o] = fmaxf(acc, 0.f);
    }
    __syncthreads();

    // write x (vectorized): 16*464 = 7424 floats = 1856 float4
    for (int idx4 = t; idx4 < 16 * (DTOT / 4); idx4 += 256) {
        const int r  = idx4 / (DTOT / 4);
        const int j4 = (idx4 - r * (DTOT / 4)) * 4;
        *(float4*)(x + (row0 + r) * DTOT + j4) = *(const float4*)&xs[r][j4];
    }
    // FM: xe[r][j] = sum_d xs[r][d] * fmW[d][j]
    if (t < 160) {
        const int r = t / 10;
        const int j = t - r * 10;
        float acc = 0.f;
        for (int d = 0; d < DTOT; ++d) acc = fmaf(xs[r][d], fmW[d * 10 + j], acc);
        xes[r][j] = acc;
    }
    __syncthreads();
    if (t < 16) {
        float s = 0.f, ss = 0.f;
#pragma unroll
        for (int j = 0; j < 10; ++j) { const float v = xes[t][j]; s += v; ss += v * v; }
        fm[row0 + t] = 0.5f * (s * s - ss);
    }
}

// ---------------------------------------------------------------------------
// Kernel 2: f32 tiled GEMM  C[z] = epi(A[z] @ W[z] + bias[z])
// BM=BN=128, BK=16, 256 threads, 8x8 per thread. N-guarded (M,K multiples ok).
// EPI_H: C[b,n] = x[b,n] + fm[b] + dot + bias  (C aliases x; in-place read ok)
// ---------------------------------------------------------------------------
enum { EPI_NONE = 0, EPI_RELU = 1, EPI_H = 2 };

template<int EPI>
__global__ __launch_bounds__(256)
void gemm_f32(const float* __restrict__ A, const float* __restrict__ W,
              const float* __restrict__ bias, float* __restrict__ C,
              int N, int K,
              long sAz, long sWz, long sBz, long sCz,
              const float* __restrict__ fmbuf)
{
    constexpr int BM = 128, BN = 128, BK = 16;
    __shared__ float As[BK][BM + 4];
    __shared__ float Ws[BK][BN];

    const int z = blockIdx.z;
    A += (long)z * sAz;
    W += (long)z * sWz;
    const float* bz = bias + (long)z * sBz;
    C += (long)z * sCz;

    const long row0 = (long)blockIdx.y * BM;
    const int  col0 = blockIdx.x * BN;
    const int  t  = threadIdx.x;
    const int  tx = t & 15, ty = t >> 4;

    float acc[8][8] = {};

    for (int k0 = 0; k0 < K; k0 += BK) {
#pragma unroll
        for (int p = 0; p < 2; ++p) {
            const int f = t + p * 256;
            const int r = f >> 2;
            const int kq = (f & 3) * 4;
            const float4 v = *(const float4*)(A + (row0 + r) * K + k0 + kq);
            As[kq + 0][r] = v.x; As[kq + 1][r] = v.y;
            As[kq + 2][r] = v.z; As[kq + 3][r] = v.w;
        }
#pragma unroll
        for (int p = 0; p < 2; ++p) {
            const int f = t + p * 256;
            const int kk = f >> 5;
            const int n4 = (f & 31) * 4;
            float4 v = make_float4(0.f, 0.f, 0.f, 0.f);
            if (col0 + n4 < N) v = *(const float4*)(W + (long)(k0 + kk) * N + col0 + n4);
            *(float4*)&Ws[kk][n4] = v;
        }
        __syncthreads();
#pragma unroll
        for (int k = 0; k < BK; ++k) {
            float a[8], b[8];
#pragma unroll
            for (int i = 0; i < 8; ++i) a[i] = As[k][ty * 8 + i];
#pragma unroll
            for (int j = 0; j < 8; ++j) b[j] = Ws[k][tx * 8 + j];
#pragma unroll
            for (int i = 0; i < 8; ++i)
#pragma unroll
                for (int j = 0; j < 8; ++j)
                    acc[i][j] = fmaf(a[i], b[j], acc[i][j]);
        }
        __syncthreads();
    }

#pragma unroll
    for (int i = 0; i < 8; ++i) {
        const long row = row0 + ty * 8 + i;
        const float fmv = (EPI == EPI_H) ? fmbuf[row] : 0.f;
#pragma unroll
        for (int j = 0; j < 8; ++j) {
            const int col = col0 + tx * 8 + j;
            if (col < N) {
                float v = acc[i][j] + bz[col];
                if (EPI == EPI_RELU) v = fmaxf(v, 0.f);
                if (EPI == EPI_H)    v = v + C[row * N + col] + fmv;
                C[row * N + col] = v;
            }
        }
    }
}

// ---------------------------------------------------------------------------
// Kernel 3: gates (softmax over experts) + mixing + task heads, fused.
// out[b,t] = sum_e g[b,t,e] * (eo[e,b,:] . taskW[t,:,0]) + taskB[t]
// One wave per row; shuffle reductions. Also appends log_vars.
// ---------------------------------------------------------------------------
__global__ __launch_bounds__(256)
void gates_mix_task(const float* __restrict__ h, const float* __restrict__ eo,
                    const float* __restrict__ gateW, const float* __restrict__ gateB,
                    const float* __restrict__ taskW, const float* __restrict__ taskB,
                    const float* __restrict__ logv, float* __restrict__ out)
{
    const int lane = threadIdx.x & 63;
    const int wv   = threadIdx.x >> 6;
    const long b   = (long)blockIdx.x * 4 + wv;

    float hreg[8];
#pragma unroll
    for (int c = 0; c < 8; ++c) {
        const int d = c * 64 + lane;
        hreg[c] = (d < DTOT) ? h[b * DTOT + d] : 0.f;
    }

    float lg[NTASK][NEXP];
#pragma unroll
    for (int tt = 0; tt < NTASK; ++tt)
#pragma unroll
        for (int e = 0; e < NEXP; ++e) lg[tt][e] = 0.f;

#pragma unroll
    for (int c = 0; c < 8; ++c) {
        const int d = c * 64 + lane;
        if (d < DTOT) {
#pragma unroll
            for (int tt = 0; tt < NTASK; ++tt) {
                const float4 gw = *(const float4*)(gateW + ((long)tt * DTOT + d) * NEXP);
                lg[tt][0] = fmaf(hreg[c], gw.x, lg[tt][0]);
                lg[tt][1] = fmaf(hreg[c], gw.y, lg[tt][1]);
                lg[tt][2] = fmaf(hreg[c], gw.z, lg[tt][2]);
                lg[tt][3] = fmaf(hreg[c], gw.w, lg[tt][3]);
            }
        }
    }

    float sv[NEXP][NTASK];
#pragma unroll
    for (int e = 0; e < NEXP; ++e) {
        const float v0 = eo[((long)e * BROWS + b) * H2S + lane];
        const float v1 = eo[((long)e * BROWS + b) * H2S + 64 + lane];
#pragma unroll
        for (int tt = 0; tt < NTASK; ++tt)
            sv[e][tt] = v0 * taskW[tt * H2S + lane] + v1 * taskW[tt * H2S + 64 + lane];
    }

#pragma unroll
    for (int off = 32; off > 0; off >>= 1) {
#pragma unroll
        for (int tt = 0; tt < NTASK; ++tt)
#pragma unroll
            for (int e = 0; e < NEXP; ++e) {
                lg[tt][e] += __shfl_xor(lg[tt][e], off, 64);
                sv[e][tt] += __shfl_xor(sv[e][tt], off, 64);
            }
    }

    if (lane == 0) {
#pragma unroll
        for (int tt = 0; tt < NTASK; ++tt) {
            const float l0 = lg[tt][0] + gateB[tt * NEXP + 0];
            const float l1 = lg[tt][1] + gateB[tt * NEXP + 1];
            const float l2 = lg[tt][2] + gateB[tt * NEXP + 2];
            const float l3 = lg[tt][3] + gateB[tt * NEXP + 3];
            const float m  = fmaxf(fmaxf(l0, l1), fmaxf(l2, l3));
            const float p0 = expf(l0 - m), p1 = expf(l1 - m);
            const float p2 = expf(l2 - m), p3 = expf(l3 - m);
            const float zs = p0 + p1 + p2 + p3;
            const float val = (p0 * sv[0][tt] + p1 * sv[1][tt] +
                               p2 * sv[2][tt] + p3 * sv[3][tt]) / zs + taskB[tt];
            out[b * NTASK + tt] = val;
        }
    }
    if (blockIdx.x == 0 && threadIdx.x < NTASK)
        out[(long)BROWS * NTASK + threadIdx.x] = logv[threadIdx.x];
}

// ---------------------------------------------------------------------------
extern "C" void kernel_launch(void* const* d_in, const int* in_sizes, int n_in,
                              void* d_out, int out_size, void* d_ws, size_t ws_size,
                              hipStream_t stream)
{
    (void)in_sizes; (void)n_in; (void)out_size; (void)ws_size;

    const int*   disc  = (const int*)  d_in[0];
    const float* cf    = (const float*)d_in[1];
    const float* emb0  = (const float*)d_in[2];
    const float* emb1  = (const float*)d_in[3];
    const float* emb2  = (const float*)d_in[4];
    const float* emb3  = (const float*)d_in[5];
    const float* emb4  = (const float*)d_in[6];
    const float* emb5  = (const float*)d_in[7];
    const float* emb6  = (const float*)d_in[8];
    const float* emb7  = (const float*)d_in[9];
    const float* contW = (const float*)d_in[10];
    const float* contB = (const float*)d_in[11];
    const float* fmW   = (const float*)d_in[12];
    const float* cW1   = (const float*)d_in[13];
    const float* cb1   = (const float*)d_in[14];
    const float* cW2   = (const float*)d_in[15];
    const float* cb2   = (const float*)d_in[16];
    const float* coW   = (const float*)d_in[17];
    const float* cob   = (const float*)d_in[18];
    const float* expW1 = (const float*)d_in[19];
    const float* expb1 = (const float*)d_in[20];
    const float* expW2 = (const float*)d_in[21];
    const float* expb2 = (const float*)d_in[22];
    const float* gateW = (const float*)d_in[23];
    const float* gateB = (const float*)d_in[24];
    const float* taskW = (const float*)d_in[25];
    const float* taskB = (const float*)d_in[26];
    const float* logv  = (const float*)d_in[27];

    float* x    = (float*)d_ws;                              // B*464 (becomes h)
    float* fm   = x + (size_t)BROWS * DTOT;                  // B
    float* bufA = fm + BROWS;                                // 4*B*256 (c1, then e1)
    float* bufB = bufA + (size_t)NEXP * BROWS * H1S;         // 4*B*128 (c2, then eo)

    // 1. x and fm
    build_x_fm<<<BROWS / 16, 256, 0, stream>>>(
        disc, cf, emb0, emb1, emb2, emb3, emb4, emb5, emb6, emb7,
        contW, contB, fmW, x, fm);

    // 2. cross1: c1 = relu(x @ cW1 + cb1)
    gemm_f32<EPI_RELU><<<dim3(H1S / 128, BROWS / 128, 1), 256, 0, stream>>>(
        x, cW1, cb1, bufA, H1S, DTOT, 0, 0, 0, 0, nullptr);
    // 3. cross2: c2 = relu(c1 @ cW2 + cb2)
    gemm_f32<EPI_RELU><<<dim3(H2S / 128, BROWS / 128, 1), 256, 0, stream>>>(
        bufA, cW2, cb2, bufB, H2S, H1S, 0, 0, 0, 0, nullptr);
    // 4. h = x + fm + (c2 @ coW + cob), written over x
    gemm_f32<EPI_H><<<dim3((DTOT + 127) / 128, BROWS / 128, 1), 256, 0, stream>>>(
        bufB, coW, cob, x, DTOT, H2S, 0, 0, 0, 0, fm);
    // 5. experts layer 1: e1[e] = relu(h @ expW1[e] + expb1[e])  -> bufA [E][B][256]
    gemm_f32<EPI_RELU><<<dim3(H1S / 128, BROWS / 128, NEXP), 256, 0, stream>>>(
        x, expW1, expb1, bufA, H1S, DTOT,
        0, (long)DTOT * H1S, H1S, (long)BROWS * H1S, nullptr);
    // 6. experts layer 2: eo[e] = e1[e] @ expW2[e] + expb2[e]   -> bufB [E][B][128]
    gemm_f32<EPI_NONE><<<dim3(H2S / 128, BROWS / 128, NEXP), 256, 0, stream>>>(
        bufA, expW2, expb2, bufB, H2S, H1S,
        (long)BROWS * H1S, (long)H1S * H2S, H2S, (long)BROWS * H2S, nullptr);
    // 7. gates + mix + task heads + log_vars
    gates_mix_task<<<BROWS / 4, 256, 0, stream>>>(
        x, bufB, gateW, gateB, taskW, taskB, logv, (float*)d_out);
}

// Round 2
// 238.635 us; speedup vs baseline: 2.4313x; 2.4313x over previous
//
#include <hip/hip_runtime.h>
#include <stdint.h>

constexpr int BROWS = 16384;
constexpr int DTOT  = 464;   // 8*50 + 64
constexpr int EDIM  = 50;
constexpr int CIN   = 64;
constexpr int H1S   = 256;
constexpr int H2S   = 128;
constexpr int NEXP  = 4;
constexpr int NTASK = 3;
constexpr int KPADX = 480;   // 464 padded to multiple of 32

typedef _Float16 f16;
typedef __attribute__((ext_vector_type(8))) _Float16 f16x8;
typedef __attribute__((ext_vector_type(4))) float    f32x4;

__device__ __forceinline__ void g2l16(const void* g, void* l) {
    __builtin_amdgcn_global_load_lds(
        (__attribute__((address_space(1))) void*)(void*)g,
        (__attribute__((address_space(3))) void*)l,
        16, 0, 0);
}

// ---------------------------------------------------------------------------
// Kernel 0: pack weight W [K][N] f32 -> Wp [Npad][Kp] f16 (transposed, 0-pad)
// ---------------------------------------------------------------------------
__global__ __launch_bounds__(256)
void pack_w(const float* __restrict__ W, f16* __restrict__ Wp,
            int K, int N, int Kp, int Npad, long sIn, long sOut)
{
    const int z = blockIdx.z;
    W  += z * sIn;
    Wp += z * sOut;
    const int idx = blockIdx.x * 256 + threadIdx.x;
    if (idx >= Npad * Kp) return;
    const int n = idx / Kp;
    const int k = idx - n * Kp;
    const float v = (n < N && k < K) ? W[(long)k * N + n] : 0.f;
    Wp[idx] = (f16)v;
}

// ---------------------------------------------------------------------------
// Kernel 1: embedding gather + continuous layer + FM term.
// Builds x32 [B,464], x16 [B,480] (0-padded), fm [B]. 16 rows per block.
// ---------------------------------------------------------------------------
__global__ __launch_bounds__(256)
void build_x_fm(const int* __restrict__ disc, const float* __restrict__ cf,
                const float* __restrict__ e0p, const float* __restrict__ e1p,
                const float* __restrict__ e2p, const float* __restrict__ e3p,
                const float* __restrict__ e4p, const float* __restrict__ e5p,
                const float* __restrict__ e6p, const float* __restrict__ e7p,
                const float* __restrict__ contW, const float* __restrict__ contB,
                const float* __restrict__ fmW,
                float* __restrict__ x, f16* __restrict__ x16,
                float* __restrict__ fm)
{
    __shared__ float xs[16][DTOT];
    __shared__ float cfs[16][CIN];
    __shared__ float xes[16][10];
    __shared__ const float* stabs[8];
    __shared__ int sdisc[16 * 8];

    const int t = threadIdx.x;
    const long row0 = (long)blockIdx.x * 16;

    if (t == 0) {
        stabs[0] = e0p; stabs[1] = e1p; stabs[2] = e2p; stabs[3] = e3p;
        stabs[4] = e4p; stabs[5] = e5p; stabs[6] = e6p; stabs[7] = e7p;
    }
    if (t < 128) sdisc[t] = disc[row0 * 8 + t];
    ((float4*)cfs)[t] = ((const float4*)(cf + row0 * CIN))[t];
    __syncthreads();

    for (int idx = t; idx < 16 * 400; idx += 256) {
        const int r   = idx / 400;
        const int j   = idx - r * 400;
        const int tab = j / 50;
        const int off = j - tab * 50;
        const long fi = sdisc[r * 8 + tab];
        xs[r][j] = stabs[tab][fi * EDIM + off];
    }
    for (int idx = t; idx < 16 * 64; idx += 256) {
        const int r = idx >> 6;
        const int o = idx & 63;
        float acc = contB[o];
#pragma unroll 8
        for (int k = 0; k < 64; ++k) acc = fmaf(cfs[r][k], contW[k * 64 + o], acc);
        xs[r][400 + o] = fmaxf(acc, 0.f);
    }
    __syncthreads();

    // x32 write (float4)
    for (int idx4 = t; idx4 < 16 * (DTOT / 4); idx4 += 256) {
        const int r  = idx4 / (DTOT / 4);
        const int j4 = (idx4 - r * (DTOT / 4)) * 4;
        *(float4*)(x + (row0 + r) * DTOT + j4) = *(const float4*)&xs[r][j4];
    }
    // x16 write (f16x8), zero-padded to 480
    for (int idx8 = t; idx8 < 16 * (KPADX / 8); idx8 += 256) {
        const int r  = idx8 / (KPADX / 8);
        const int j8 = (idx8 - r * (KPADX / 8)) * 8;
        f16x8 v;
#pragma unroll
        for (int q = 0; q < 8; ++q)
            v[q] = (j8 + q < DTOT) ? (f16)xs[r][j8 + q] : (f16)0.f;
        *(f16x8*)(x16 + (row0 + r) * KPADX + j8) = v;
    }
    // FM
    if (t < 160) {
        const int r = t / 10;
        const int j = t - r * 10;
        float acc = 0.f;
        for (int d = 0; d < DTOT; ++d) acc = fmaf(xs[r][d], fmW[d * 10 + j], acc);
        xes[r][j] = acc;
    }
    __syncthreads();
    if (t < 16) {
        float s = 0.f, ss = 0.f;
#pragma unroll
        for (int j = 0; j < 10; ++j) { const float v = xes[t][j]; s += v; ss += v * v; }
        fm[row0 + t] = 0.5f * (s * s - ss);
    }
}

// ---------------------------------------------------------------------------
// Kernel 2: f16 MFMA GEMM. C = epi(A @ Wp^T + bias).
// A [M][Kp] f16 row-major (Kp mult of 32, 0-padded). Wp [Npad][Kp] f16.
// BM=BN=128, BK=32, 256 thr = 4 waves, each wave 64x64 (4x4 frags 16x16).
// LDS [kc][row][8] lane-linear; staged via global_load_lds width 16.
// EPI_H: v += C32[row][col] + fm[row] (C32 = x32 in-place), dual write.
// ---------------------------------------------------------------------------
enum { EPI_NONE = 0, EPI_RELU = 1, EPI_H = 2 };

template<int EPI>
__global__ __launch_bounds__(256)
void gemm_mfma(const f16* __restrict__ A, const f16* __restrict__ Wp,
               const float* __restrict__ bias,
               float* __restrict__ C32, f16* __restrict__ C16,
               int N, int Kp, int ldc16,
               long sAz, long sWz, long sBz, long sC32z, long sC16z,
               const float* __restrict__ fmbuf)
{
    __shared__ f16 Als[4][128][8];
    __shared__ f16 Bls[4][128][8];

    const int z = blockIdx.z;
    A  += z * sAz;
    Wp += z * sWz;
    const float* bz = bias + z * sBz;
    if (C32) C32 += z * sC32z;
    if (C16) C16 += z * sC16z;

    const int t    = threadIdx.x;
    const int lane = t & 63;
    const int wave = t >> 6;
    const int wm   = wave >> 1;      // 0..1
    const int wn   = wave & 1;       // 0..1
    const long row0 = (long)blockIdx.y * 128;
    const int  col0 = blockIdx.x * 128;

    const int g  = lane >> 4;        // k-chunk group 0..3
    const int rr = lane & 15;

    f32x4 acc[4][4] = {};

    const int nkb = Kp >> 5;
    for (int kb = 0; kb < nkb; ++kb) {
        const long koff = (long)kb * 32 + wave * 8;
        // A tile: wave stages kc=wave, rows [0..127]
        g2l16(A + (row0 + lane) * Kp + koff,      &Als[wave][0][0]);
        g2l16(A + (row0 + 64 + lane) * Kp + koff, &Als[wave][64][0]);
        // B tile: wave stages kc=wave, cols [0..127]
        g2l16(Wp + (long)(col0 + lane) * Kp + koff,      &Bls[wave][0][0]);
        g2l16(Wp + (long)(col0 + 64 + lane) * Kp + koff, &Bls[wave][64][0]);
        __syncthreads();

        f16x8 af[4], bf[4];
#pragma unroll
        for (int i = 0; i < 4; ++i)
            af[i] = *(const f16x8*)&Als[g][wm * 64 + i * 16 + rr][0];
#pragma unroll
        for (int j = 0; j < 4; ++j)
            bf[j] = *(const f16x8*)&Bls[g][wn * 64 + j * 16 + rr][0];
#pragma unroll
        for (int i = 0; i < 4; ++i)
#pragma unroll
            for (int j = 0; j < 4; ++j)
                acc[i][j] = __builtin_amdgcn_mfma_f32_16x16x32_f16(
                    af[i], bf[j], acc[i][j], 0, 0, 0);
        __syncthreads();
    }

#pragma unroll
    for (int i = 0; i < 4; ++i) {
#pragma unroll
        for (int j = 0; j < 4; ++j) {
            const int col = col0 + wn * 64 + j * 16 + rr;
            if (col < N) {
                const float bv = bz[col];
#pragma unroll
                for (int r = 0; r < 4; ++r) {
                    const long row = row0 + wm * 64 + i * 16 + g * 4 + r;
                    float v = acc[i][j][r] + bv;
                    if (EPI == EPI_RELU) v = fmaxf(v, 0.f);
                    if (EPI == EPI_H)    v += C32[row * N + col] + fmbuf[row];
                    if (C32) C32[row * (long)N + col] = v;
                    if (C16) C16[row * (long)ldc16 + col] = (f16)v;
                }
            }
        }
    }
}

// ---------------------------------------------------------------------------
// Kernel 3: gates (softmax over experts) + mixing + task heads, fused.
// ---------------------------------------------------------------------------
__global__ __launch_bounds__(256)
void gates_mix_task(const float* __restrict__ h, const float* __restrict__ eo,
                    const float* __restrict__ gateW, const float* __restrict__ gateB,
                    const float* __restrict__ taskW, const float* __restrict__ taskB,
                    const float* __restrict__ logv, float* __restrict__ out)
{
    const int lane = threadIdx.x & 63;
    const int wv   = threadIdx.x >> 6;
    const long b   = (long)blockIdx.x * 4 + wv;

    float hreg[8];
#pragma unroll
    for (int c = 0; c < 8; ++c) {
        const int d = c * 64 + lane;
        hreg[c] = (d < DTOT) ? h[b * DTOT + d] : 0.f;
    }

    float lg[NTASK][NEXP];
#pragma unroll
    for (int tt = 0; tt < NTASK; ++tt)
#pragma unroll
        for (int e = 0; e < NEXP; ++e) lg[tt][e] = 0.f;

#pragma unroll
    for (int c = 0; c < 8; ++c) {
        const int d = c * 64 + lane;
        if (d < DTOT) {
#pragma unroll
            for (int tt = 0; tt < NTASK; ++tt) {
                const float4 gw = *(const float4*)(gateW + ((long)tt * DTOT + d) * NEXP);
                lg[tt][0] = fmaf(hreg[c], gw.x, lg[tt][0]);
                lg[tt][1] = fmaf(hreg[c], gw.y, lg[tt][1]);
                lg[tt][2] = fmaf(hreg[c], gw.z, lg[tt][2]);
                lg[tt][3] = fmaf(hreg[c], gw.w, lg[tt][3]);
            }
        }
    }

    float sv[NEXP][NTASK];
#pragma unroll
    for (int e = 0; e < NEXP; ++e) {
        const float v0 = eo[((long)e * BROWS + b) * H2S + lane];
        const float v1 = eo[((long)e * BROWS + b) * H2S + 64 + lane];
#pragma unroll
        for (int tt = 0; tt < NTASK; ++tt)
            sv[e][tt] = v0 * taskW[tt * H2S + lane] + v1 * taskW[tt * H2S + 64 + lane];
    }

#pragma unroll
    for (int off = 32; off > 0; off >>= 1) {
#pragma unroll
        for (int tt = 0; tt < NTASK; ++tt)
#pragma unroll
            for (int e = 0; e < NEXP; ++e) {
                lg[tt][e] += __shfl_xor(lg[tt][e], off, 64);
                sv[e][tt] += __shfl_xor(sv[e][tt], off, 64);
            }
    }

    if (lane == 0) {
#pragma unroll
        for (int tt = 0; tt < NTASK; ++tt) {
            const float l0 = lg[tt][0] + gateB[tt * NEXP + 0];
            const float l1 = lg[tt][1] + gateB[tt * NEXP + 1];
            const float l2 = lg[tt][2] + gateB[tt * NEXP + 2];
            const float l3 = lg[tt][3] + gateB[tt * NEXP + 3];
            const float m  = fmaxf(fmaxf(l0, l1), fmaxf(l2, l3));
            const float p0 = expf(l0 - m), p1 = expf(l1 - m);
            const float p2 = expf(l2 - m), p3 = expf(l3 - m);
            const float zs = p0 + p1 + p2 + p3;
            const float val = (p0 * sv[0][tt] + p1 * sv[1][tt] +
                               p2 * sv[2][tt] + p3 * sv[3][tt]) / zs + taskB[tt];
            out[b * NTASK + tt] = val;
        }
    }
    if (blockIdx.x == 0 && threadIdx.x < NTASK)
        out[(long)BROWS * NTASK + threadIdx.x] = logv[threadIdx.x];
}

// ---------------------------------------------------------------------------
extern "C" void kernel_launch(void* const* d_in, const int* in_sizes, int n_in,
                              void* d_out, int out_size, void* d_ws, size_t ws_size,
                              hipStream_t stream)
{
    (void)in_sizes; (void)n_in; (void)out_size; (void)ws_size;

    const int*   disc  = (const int*)  d_in[0];
    const float* cf    = (const float*)d_in[1];
    const float* emb0  = (const float*)d_in[2];
    const float* emb1  = (const float*)d_in[3];
    const float* emb2  = (const float*)d_in[4];
    const float* emb3  = (const float*)d_in[5];
    const float* emb4  = (const float*)d_in[6];
    const float* emb5  = (const float*)d_in[7];
    const float* emb6  = (const float*)d_in[8];
    const float* emb7  = (const float*)d_in[9];
    const float* contW = (const float*)d_in[10];
    const float* contB = (const float*)d_in[11];
    const float* fmW   = (const float*)d_in[12];
    const float* cW1   = (const float*)d_in[13];
    const float* cb1   = (const float*)d_in[14];
    const float* cW2   = (const float*)d_in[15];
    const float* cb2   = (const float*)d_in[16];
    const float* coW   = (const float*)d_in[17];
    const float* cob   = (const float*)d_in[18];
    const float* expW1 = (const float*)d_in[19];
    const float* expb1 = (const float*)d_in[20];
    const float* expW2 = (const float*)d_in[21];
    const float* expb2 = (const float*)d_in[22];
    const float* gateW = (const float*)d_in[23];
    const float* gateB = (const float*)d_in[24];
    const float* taskW = (const float*)d_in[25];
    const float* taskB = (const float*)d_in[26];
    const float* logv  = (const float*)d_in[27];

    char* w = (char*)d_ws;
    float* x32 = (float*)w;  w += (size_t)BROWS * DTOT * 4;
    float* fm  = (float*)w;  w += (size_t)BROWS * 4;
    float* eo  = (float*)w;  w += (size_t)NEXP * BROWS * H2S * 4;
    f16* x16   = (f16*)w;    w += (size_t)BROWS * KPADX * 2;
    f16* e1h   = (f16*)w;    w += (size_t)NEXP * BROWS * H1S * 2;   // c1 = slice 0
    f16* c2h   = (f16*)w;    w += (size_t)BROWS * H2S * 2;
    f16* cW1p  = (f16*)w;    w += (size_t)H1S * KPADX * 2;          // [256][480]
    f16* cW2p  = (f16*)w;    w += (size_t)H2S * H1S * 2;            // [128][256]
    f16* coWp  = (f16*)w;    w += (size_t)512 * H2S * 2;            // [512][128]
    f16* eW1p  = (f16*)w;    w += (size_t)NEXP * H1S * KPADX * 2;   // [4][256][480]
    f16* eW2p  = (f16*)w;    w += (size_t)NEXP * H2S * H1S * 2;     // [4][128][256]

    // 0. pack weights to f16, transposed [Npad][Kp]
    pack_w<<<dim3((H1S * KPADX + 255) / 256, 1, 1), 256, 0, stream>>>(
        cW1, cW1p, DTOT, H1S, KPADX, H1S, 0, 0);
    pack_w<<<dim3((H2S * H1S + 255) / 256, 1, 1), 256, 0, stream>>>(
        cW2, cW2p, H1S, H2S, H1S, H2S, 0, 0);
    pack_w<<<dim3((512 * H2S + 255) / 256, 1, 1), 256, 0, stream>>>(
        coW, coWp, H2S, DTOT, H2S, 512, 0, 0);
    pack_w<<<dim3((H1S * KPADX + 255) / 256, 1, NEXP), 256, 0, stream>>>(
        expW1, eW1p, DTOT, H1S, KPADX, H1S, (long)DTOT * H1S, (long)H1S * KPADX);
    pack_w<<<dim3((H2S * H1S + 255) / 256, 1, NEXP), 256, 0, stream>>>(
        expW2, eW2p, H1S, H2S, H1S, H2S, (long)H1S * H2S, (long)H2S * H1S);

    // 1. x (f32 + f16) and fm
    build_x_fm<<<BROWS / 16, 256, 0, stream>>>(
        disc, cf, emb0, emb1, emb2, emb3, emb4, emb5, emb6, emb7,
        contW, contB, fmW, x32, x16, fm);

    // 2. cross1: c1 = relu(x @ cW1 + cb1)  -> f16 only
    gemm_mfma<EPI_RELU><<<dim3(2, 128, 1), 256, 0, stream>>>(
        x16, cW1p, cb1, nullptr, e1h, H1S, KPADX, H1S,
        0, 0, 0, 0, 0, nullptr);
    // 3. cross2: c2 = relu(c1 @ cW2 + cb2) -> f16 only
    gemm_mfma<EPI_RELU><<<dim3(1, 128, 1), 256, 0, stream>>>(
        e1h, cW2p, cb2, nullptr, c2h, H2S, H1S, H2S,
        0, 0, 0, 0, 0, nullptr);
    // 4. h = x + fm + (c2 @ coW + cob) -> x32 (in-place) and x16
    gemm_mfma<EPI_H><<<dim3(4, 128, 1), 256, 0, stream>>>(
        c2h, coWp, cob, x32, x16, DTOT, H2S, KPADX,
        0, 0, 0, 0, 0, fm);
    // 5. experts1: e1[e] = relu(h @ expW1[e] + expb1[e]) -> f16 [4][B][256]
    gemm_mfma<EPI_RELU><<<dim3(2, 128, NEXP), 256, 0, stream>>>(
        x16, eW1p, expb1, nullptr, e1h, H1S, KPADX, H1S,
        0, (long)H1S * KPADX, H1S, 0, (long)BROWS * H1S, nullptr);
    // 6. experts2: eo[e] = e1[e] @ expW2[e] + expb2[e] -> f32 [4][B][128]
    gemm_mfma<EPI_NONE><<<dim3(1, 128, NEXP), 256, 0, stream>>>(
        e1h, eW2p, expb2, eo, nullptr, H2S, H1S, H2S,
        (long)BROWS * H1S, (long)H2S * H1S, H2S, (long)BROWS * H2S, 0, nullptr);

    // 7. gates + mix + task heads + log_vars
    gates_mix_task<<<BROWS / 4, 256, 0, stream>>>(
        x32, eo, gateW, gateB, taskW, taskB, logv, (float*)d_out);
}

// Round 4
// 100.744 us; speedup vs baseline: 5.7592x; 2.3687x over previous
//
#include <hip/hip_runtime.h>
#include <stdint.h>

typedef _Float16 f16;
typedef __attribute__((ext_vector_type(8))) _Float16 f16x8;
typedef __attribute__((ext_vector_type(4))) float    f32x4;

constexpr int BROWS = 16384;
constexpr int NTASK = 3;

// ---- packed-weight layout in d_ws (f16 elements) ----
constexpr int OFF_CW1 = 0;                       // [256][480]
constexpr int OFF_CW2 = OFF_CW1 + 256 * 480;     // [128][256]
constexpr int OFF_COW = OFF_CW2 + 128 * 256;     // [512][128]
constexpr int OFF_EW1 = OFF_COW + 512 * 128;     // [1024][480]  (4 experts x 256)
constexpr int OFF_EW2 = OFF_EW1 + 1024 * 480;    // [512][256]   (4 experts x 128)
constexpr int OFF_FMW = OFF_EW2 + 512 * 256;     // [16][480]
constexpr int OFF_GW  = OFF_FMW + 16 * 480;      // [16][480]
constexpr int OFF_CTW = OFF_GW  + 16 * 480;      // [64][64]
constexpr int PACK_TOTAL = OFF_CTW + 64 * 64;    // 863,232 f16 = 1.73 MB

// ---------------------------------------------------------------------------
// Kernel 0: pack ALL weights to f16, transposed [N][K], zero-padded. 1 launch.
// ---------------------------------------------------------------------------
__global__ __launch_bounds__(256)
void pack_all(const float* __restrict__ cW1, const float* __restrict__ cW2,
              const float* __restrict__ coW, const float* __restrict__ expW1,
              const float* __restrict__ expW2, const float* __restrict__ fmW,
              const float* __restrict__ gateW, const float* __restrict__ contW,
              f16* __restrict__ wp)
{
    const int idx = blockIdx.x * 256 + threadIdx.x;
    if (idx >= PACK_TOTAL) return;
    float v = 0.f;
    if (idx < OFF_CW2) {                       // cW1 (464,256)
        const int l = idx - OFF_CW1, n = l / 480, k = l % 480;
        if (k < 464) v = cW1[k * 256 + n];
    } else if (idx < OFF_COW) {                // cW2 (256,128)
        const int l = idx - OFF_CW2, n = l / 256, k = l % 256;
        v = cW2[k * 128 + n];
    } else if (idx < OFF_EW1) {                // coW (128,464), Npad 512
        const int l = idx - OFF_COW, n = l / 128, k = l % 128;
        if (n < 464) v = coW[k * 464 + n];
    } else if (idx < OFF_EW2) {                // expW1 (4,464,256)
        const int l = idx - OFF_EW1, n = l / 480, k = l % 480;
        const int e = n >> 8, nn = n & 255;
        if (k < 464) v = expW1[(e * 464 + k) * 256 + nn];
    } else if (idx < OFF_FMW) {                // expW2 (4,256,128)
        const int l = idx - OFF_EW2, n = l / 256, k = l % 256;
        const int e = n >> 7, nn = n & 127;
        v = expW2[(e * 256 + k) * 128 + nn];
    } else if (idx < OFF_GW) {                 // fmW (464,10) -> [16][480]
        const int l = idx - OFF_FMW, c = l / 480, k = l % 480;
        if (c < 10 && k < 464) v = fmW[k * 10 + c];
    } else if (idx < OFF_CTW) {                // gateW (3,464,4) -> [16][480]
        const int l = idx - OFF_GW, c = l / 480, k = l % 480;
        if (c < 12 && k < 464) {
            const int tt = c >> 2, e = c & 3;
            v = gateW[(tt * 464 + k) * 4 + e];
        }
    } else {                                   // contW (64,64) -> [64][64]
        const int l = idx - OFF_CTW, n = l / 64, k = l % 64;
        v = contW[k * 64 + n];
    }
    wp[idx] = (f16)v;
}

// ---------------------------------------------------------------------------
// wave-level GEMM helper: acc[MF][NF] (+)= A_lds @ B_glb^T over KS k-steps.
// A-frag: lane (l&15)=row, (l>>4)*8=k-chunk. B from global [N][ldb] f16.
// D layout: col = l&15, row = (l>>4)*4 + reg (HW-verified m89 / round-2 pass).
// ---------------------------------------------------------------------------
template<int MF, int NF, int KS, int LDA>
__device__ __forceinline__ void wave_gemm(
    const f16* __restrict__ As, int arow0,
    const f16* __restrict__ Bg, int bcol0, int ldb,
    f32x4 (&acc)[MF][NF], int lane)
{
    const int g = lane >> 4, rr = lane & 15;
#pragma unroll
    for (int kb = 0; kb < KS; ++kb) {
        const int ko = kb * 32 + g * 8;
        f16x8 bf[NF];
#pragma unroll
        for (int j = 0; j < NF; ++j)
            bf[j] = *(const f16x8*)(Bg + (long)(bcol0 + j * 16 + rr) * ldb + ko);
#pragma unroll
        for (int i = 0; i < MF; ++i) {
            const f16x8 af = *(const f16x8*)(As + (arow0 + i * 16 + rr) * LDA + ko);
#pragma unroll
            for (int j = 0; j < NF; ++j)
                acc[i][j] = __builtin_amdgcn_mfma_f32_16x16x32_f16(
                    af, bf[j], acc[i][j], 0, 0, 0);
        }
    }
}

// ---------------------------------------------------------------------------
// Kernel 1: the entire MMoE forward for 64 rows per block, 256 blocks.
// ---------------------------------------------------------------------------
__global__ __launch_bounds__(256, 1)
void mmoe_fused(const int* __restrict__ disc, const float* __restrict__ cf,
                const float* __restrict__ e0p, const float* __restrict__ e1p,
                const float* __restrict__ e2p, const float* __restrict__ e3p,
                const float* __restrict__ e4p, const float* __restrict__ e5p,
                const float* __restrict__ e6p, const float* __restrict__ e7p,
                const float* __restrict__ contB, const float* __restrict__ cb1,
                const float* __restrict__ cb2, const float* __restrict__ cob,
                const float* __restrict__ expb1, const float* __restrict__ expb2,
                const float* __restrict__ gateB, const float* __restrict__ taskW,
                const float* __restrict__ taskB, const float* __restrict__ logv,
                const f16* __restrict__ wp, float* __restrict__ out)
{
    __shared__ f16   sh_x [64][488];   // x, later h (cols 464..487 zero)
    __shared__ f16   sh_c1[64][264];   // c1 / e1
    __shared__ f16   sh_c2[64][136];   // c2 (cf staging aliases this)
    __shared__ float sh_g [64][12];    // gate probs
    __shared__ float sh_part[4][64][3];
    __shared__ float sh_fm[64];
    __shared__ const float* stabs[8];

    const int t = threadIdx.x;
    const int lane = t & 63, wave = t >> 6;
    const int g = lane >> 4, rr = lane & 15;
    const long r0 = (long)blockIdx.x * 64;

    const f16* cW1p = wp + OFF_CW1;
    const f16* cW2p = wp + OFF_CW2;
    const f16* coWp = wp + OFF_COW;
    const f16* eW1p = wp + OFF_EW1;
    const f16* eW2p = wp + OFF_EW2;
    const f16* fmWp = wp + OFF_FMW;
    const f16* gWp  = wp + OFF_GW;
    const f16* ctWp = wp + OFF_CTW;

    if (t == 0) {
        stabs[0] = e0p; stabs[1] = e1p; stabs[2] = e2p; stabs[3] = e3p;
        stabs[4] = e4p; stabs[5] = e5p; stabs[6] = e6p; stabs[7] = e7p;
    }
    __syncthreads();

    // ---- P0a: zero-pad x, gather embeddings, stage cf as f16 ----
    f16* cfp = (f16*)&sh_c2[0][0];                       // [64][72]
    for (int i = t; i < 64 * 24; i += 256) sh_x[i / 24][464 + i % 24] = (f16)0.f;
    for (int p = t; p < 512; p += 256) {                 // (row, table) pairs
        const int r = p >> 3, tab = p & 7;
        const long fi = disc[(r0 + r) * 8 + tab];
        const float* src = stabs[tab] + fi * 50;
        f16* dst = &sh_x[r][tab * 50];
#pragma unroll
        for (int q = 0; q < 25; ++q) {
            const float2 v = *(const float2*)(src + q * 2);
            dst[q * 2] = (f16)v.x; dst[q * 2 + 1] = (f16)v.y;
        }
    }
    for (int i = t; i < 64 * 16; i += 256) {             // cf [64][64] f32 -> f16
        const int r = i >> 4, q = i & 15;
        const float4 v = *(const float4*)(cf + (r0 + r) * 64 + q * 4);
        f16* dst = cfp + r * 72 + q * 4;
        dst[0] = (f16)v.x; dst[1] = (f16)v.y; dst[2] = (f16)v.z; dst[3] = (f16)v.w;
    }
    __syncthreads();

    // ---- P0b: cont = relu(cf @ contW + b) -> sh_x[:,400:464] ----
    {
        f32x4 acc[4][1] = {};
        wave_gemm<4, 1, 2, 72>(cfp, 0, ctWp, wave * 16, 64, acc, lane);
        const int col = wave * 16 + rr;
        const float bv = contB[col];
#pragma unroll
        for (int i = 0; i < 4; ++i)
#pragma unroll
            for (int rx = 0; rx < 4; ++rx)
                sh_x[i * 16 + g * 4 + rx][400 + col] =
                    (f16)fmaxf(acc[i][0][rx] + bv, 0.f);
    }
    __syncthreads();

    // ---- P0c: FM + c1 (both read-only on sh_x) ----
    {   // FM: xe = x @ fmW [16 cols, 10 used]; fm = .5*((Σxe)^2 - Σxe^2)
        f32x4 a[1][1] = {};
        wave_gemm<1, 1, 15, 488>(&sh_x[0][0], wave * 16, fmWp, 0, 480, a, lane);
#pragma unroll
        for (int rx = 0; rx < 4; ++rx) {
            const float v = a[0][0][rx];
            float s = v, ss = v * v;
#pragma unroll
            for (int off = 1; off < 16; off <<= 1) {
                s += __shfl_xor(s, off, 64); ss += __shfl_xor(ss, off, 64);
            }
            if (rr == 0) sh_fm[wave * 16 + g * 4 + rx] = 0.5f * (s * s - ss);
        }
    }
    {   // c1 = relu(x @ cW1 + cb1)
        f32x4 acc[4][4] = {};
        wave_gemm<4, 4, 15, 488>(&sh_x[0][0], 0, cW1p, wave * 64, 480, acc, lane);
#pragma unroll
        for (int j = 0; j < 4; ++j) {
            const int col = wave * 64 + j * 16 + rr;
            const float bv = cb1[col];
#pragma unroll
            for (int i = 0; i < 4; ++i)
#pragma unroll
                for (int rx = 0; rx < 4; ++rx)
                    sh_c1[i * 16 + g * 4 + rx][col] =
                        (f16)fmaxf(acc[i][j][rx] + bv, 0.f);
        }
    }
    __syncthreads();

    // ---- P2: c2 = relu(c1 @ cW2 + cb2) ----
    {
        f32x4 acc[4][2] = {};
        wave_gemm<4, 2, 8, 264>(&sh_c1[0][0], 0, cW2p, wave * 32, 256, acc, lane);
#pragma unroll
        for (int j = 0; j < 2; ++j) {
            const int col = wave * 32 + j * 16 + rr;
            const float bv = cb2[col];
#pragma unroll
            for (int i = 0; i < 4; ++i)
#pragma unroll
                for (int rx = 0; rx < 4; ++rx)
                    sh_c2[i * 16 + g * 4 + rx][col] =
                        (f16)fmaxf(acc[i][j][rx] + bv, 0.f);
        }
    }
    __syncthreads();

    // ---- P3: h = x + (c2 @ coW + cob) + fm  (in-place into sh_x) ----
    {
        f32x4 acc[4][8] = {};
        wave_gemm<4, 8, 4, 136>(&sh_c2[0][0], 0, coWp, wave * 128, 128, acc, lane);
#pragma unroll
        for (int j = 0; j < 8; ++j) {
            const int col = wave * 128 + j * 16 + rr;
            if (col < 464) {
                const float bv = cob[col];
#pragma unroll
                for (int i = 0; i < 4; ++i)
#pragma unroll
                    for (int rx = 0; rx < 4; ++rx) {
                        const int row = i * 16 + g * 4 + rx;
                        const float v = acc[i][j][rx] + bv +
                                        (float)sh_x[row][col] + sh_fm[row];
                        sh_x[row][col] = (f16)v;
                    }
            }
        }
    }
    __syncthreads();

    // ---- gates: softmax_e(h @ gateW + gb) -> sh_g (uses h!) ----
    {
        f32x4 a[1][1] = {};
        wave_gemm<1, 1, 15, 488>(&sh_x[0][0], wave * 16, gWp, 0, 480, a, lane);
        const float gb = (rr < 12) ? gateB[rr] : 0.f;
#pragma unroll
        for (int rx = 0; rx < 4; ++rx) {
            const float v = a[0][0][rx] + gb;
            float m = fmaxf(v, __shfl_xor(v, 1, 64));
            m = fmaxf(m, __shfl_xor(m, 2, 64));
            const float p = __expf(v - m);
            float s = p + __shfl_xor(p, 1, 64);
            s += __shfl_xor(s, 2, 64);
            if (rr < 12) sh_g[wave * 16 + g * 4 + rx][rr] = p / s;
        }
    }
    __syncthreads();

    // ---- experts: e1 = relu(h@W1+b1); out += g_e * ((e1@W2+b2) . taskW) ----
    float tw[3][2];
#pragma unroll
    for (int tt = 0; tt < 3; ++tt) {
        tw[tt][0] = taskW[tt * 128 + wave * 32 + rr];
        tw[tt][1] = taskW[tt * 128 + wave * 32 + 16 + rr];
    }
    float oacc[4][4][3];
#pragma unroll
    for (int i = 0; i < 4; ++i)
#pragma unroll
        for (int rx = 0; rx < 4; ++rx)
#pragma unroll
            for (int tt = 0; tt < 3; ++tt) oacc[i][rx][tt] = 0.f;

#pragma unroll 1
    for (int e = 0; e < 4; ++e) {
        {   // e1 -> sh_c1
            f32x4 acc[4][4] = {};
            wave_gemm<4, 4, 15, 488>(&sh_x[0][0], 0, eW1p + e * (256 * 480),
                                     wave * 64, 480, acc, lane);
#pragma unroll
            for (int j = 0; j < 4; ++j) {
                const int col = wave * 64 + j * 16 + rr;
                const float bv = expb1[e * 256 + col];
#pragma unroll
                for (int i = 0; i < 4; ++i)
#pragma unroll
                    for (int rx = 0; rx < 4; ++rx)
                        sh_c1[i * 16 + g * 4 + rx][col] =
                            (f16)fmaxf(acc[i][j][rx] + bv, 0.f);
            }
        }
        __syncthreads();
        {   // eo (regs only) -> task dot -> gated accumulate
            f32x4 acc[4][2] = {};
            wave_gemm<4, 2, 8, 264>(&sh_c1[0][0], 0, eW2p + e * (128 * 256),
                                    wave * 32, 256, acc, lane);
            const float bv0 = expb2[e * 128 + wave * 32 + rr];
            const float bv1 = expb2[e * 128 + wave * 32 + 16 + rr];
#pragma unroll
            for (int i = 0; i < 4; ++i)
#pragma unroll
                for (int rx = 0; rx < 4; ++rx) {
                    const int row = i * 16 + g * 4 + rx;
                    const float v0 = acc[i][0][rx] + bv0;
                    const float v1 = acc[i][1][rx] + bv1;
#pragma unroll
                    for (int tt = 0; tt < 3; ++tt) {
                        float s = v0 * tw[tt][0] + v1 * tw[tt][1];
#pragma unroll
                        for (int off = 1; off < 16; off <<= 1)
                            s += __shfl_xor(s, off, 64);
                        oacc[i][rx][tt] += sh_g[row][tt * 4 + e] * s;
                    }
                }
        }
        __syncthreads();
    }

    // ---- final: cross-wave reduce (waves hold disjoint 32-col partials) ----
    if (rr == 0) {
#pragma unroll
        for (int i = 0; i < 4; ++i)
#pragma unroll
            for (int rx = 0; rx < 4; ++rx)
#pragma unroll
                for (int tt = 0; tt < 3; ++tt)
                    sh_part[wave][i * 16 + g * 4 + rx][tt] = oacc[i][rx][tt];
    }
    __syncthreads();
    for (int i = t; i < 64 * 3; i += 256) {
        const int row = i / 3, tt = i - row * 3;
        out[(r0 + row) * 3 + tt] = sh_part[0][row][tt] + sh_part[1][row][tt] +
                                   sh_part[2][row][tt] + sh_part[3][row][tt] +
                                   taskB[tt];
    }
    if (blockIdx.x == 0 && t < NTASK) out[(long)BROWS * 3 + t] = logv[t];
}

// ---------------------------------------------------------------------------
extern "C" void kernel_launch(void* const* d_in, const int* in_sizes, int n_in,
                              void* d_out, int out_size, void* d_ws, size_t ws_size,
                              hipStream_t stream)
{
    (void)in_sizes; (void)n_in; (void)out_size; (void)ws_size;

    const int*   disc  = (const int*)  d_in[0];
    const float* cf    = (const float*)d_in[1];
    const float* emb0  = (const float*)d_in[2];
    const float* emb1  = (const float*)d_in[3];
    const float* emb2  = (const float*)d_in[4];
    const float* emb3  = (const float*)d_in[5];
    const float* emb4  = (const float*)d_in[6];
    const float* emb5  = (const float*)d_in[7];
    const float* emb6  = (const float*)d_in[8];
    const float* emb7  = (const float*)d_in[9];
    const float* contW = (const float*)d_in[10];
    const float* contB = (const float*)d_in[11];
    const float* fmW   = (const float*)d_in[12];
    const float* cW1   = (const float*)d_in[13];
    const float* cb1   = (const float*)d_in[14];
    const float* cW2   = (const float*)d_in[15];
    const float* cb2   = (const float*)d_in[16];
    const float* coW   = (const float*)d_in[17];
    const float* cob   = (const float*)d_in[18];
    const float* expW1 = (const float*)d_in[19];
    const float* expb1 = (const float*)d_in[20];
    const float* expW2 = (const float*)d_in[21];
    const float* expb2 = (const float*)d_in[22];
    const float* gateW = (const float*)d_in[23];
    const float* gateB = (const float*)d_in[24];
    const float* taskW = (const float*)d_in[25];
    const float* taskB = (const float*)d_in[26];
    const float* logv  = (const float*)d_in[27];

    f16* wp = (f16*)d_ws;

    pack_all<<<(PACK_TOTAL + 255) / 256, 256, 0, stream>>>(
        cW1, cW2, coW, expW1, expW2, fmW, gateW, contW, wp);

    mmoe_fused<<<BROWS / 64, 256, 0, stream>>>(
        disc, cf, emb0, emb1, emb2, emb3, emb4, emb5, emb6, emb7,
        contB, cb1, cb2, cob, expb1, expb2, gateB, taskW, taskB, logv,
        wp, (float*)d_out);
}